// Round 3
// baseline (483.005 us; speedup 1.0000x reference)
//
#include <hip/hip_runtime.h>

#define THREADS 256

// ---------------- CSR build ----------------

// counts + per-target rank (atomic return value)
__global__ __launch_bounds__(THREADS) void k_hist2(const int* __restrict__ tgt,
                                                   int* __restrict__ cnt,
                                                   int* __restrict__ ke, int E) {
    int e = blockIdx.x * THREADS + threadIdx.x;
    if (e < E) ke[e] = atomicAdd(&cnt[tgt[e]], 1);
}

// per-1024-chunk totals
__global__ __launch_bounds__(THREADS) void k_scan_partial(const int* __restrict__ cnt,
                                                          int* __restrict__ bsum, int N) {
    __shared__ int lds[THREADS];
    int base = blockIdx.x * 1024 + threadIdx.x * 4;
    int s = 0;
    #pragma unroll
    for (int k = 0; k < 4; ++k) { int i = base + k; if (i < N) s += cnt[i]; }
    lds[threadIdx.x] = s; __syncthreads();
    for (int off = THREADS / 2; off > 0; off >>= 1) {
        if (threadIdx.x < off) lds[threadIdx.x] += lds[threadIdx.x + off];
        __syncthreads();
    }
    if (threadIdx.x == 0) bsum[blockIdx.x] = lds[0];
}

// single-block exclusive scan of block sums (NB <= 1024)
__global__ __launch_bounds__(1024) void k_scan_bsum(int* __restrict__ bsum, int NB) {
    __shared__ int lds[1024];
    int t = threadIdx.x;
    int v = (t < NB) ? bsum[t] : 0;
    lds[t] = v; __syncthreads();
    for (int off = 1; off < 1024; off <<= 1) {
        int x = (t >= off) ? lds[t - off] : 0;
        __syncthreads();
        lds[t] += x;
        __syncthreads();
    }
    if (t < NB) bsum[t] = lds[t] - v;   // exclusive
}

__global__ __launch_bounds__(THREADS) void k_scan_final(int* __restrict__ cnt,
                                                        const int* __restrict__ bsum,
                                                        int* __restrict__ rowptr,
                                                        int N, int E) {
    __shared__ int lds[THREADS];
    int base = blockIdx.x * 1024 + threadIdx.x * 4;
    int v[4]; int local = 0;
    #pragma unroll
    for (int k = 0; k < 4; ++k) {
        int i = base + k;
        v[k] = (i < N) ? cnt[i] : 0;
        local += v[k];
    }
    lds[threadIdx.x] = local; __syncthreads();
    for (int off = 1; off < THREADS; off <<= 1) {
        int x = (threadIdx.x >= off) ? lds[threadIdx.x - off] : 0;
        __syncthreads();
        lds[threadIdx.x] += x;
        __syncthreads();
    }
    int p = lds[threadIdx.x] - local + bsum[blockIdx.x];
    #pragma unroll
    for (int k = 0; k < 4; ++k) {
        int i = base + k;
        if (i < N) { rowptr[i] = p; p += v[k]; }
    }
    if (blockIdx.x == 0 && threadIdx.x == 0) rowptr[N] = E;
}

// scatter edge ids into CSR order -- no atomics (rank precomputed)
__global__ __launch_bounds__(THREADS) void k_perm(const int* __restrict__ tgt,
                                                  const int* __restrict__ ke,
                                                  const int* __restrict__ rowptr,
                                                  int* __restrict__ perm, int E) {
    int e = blockIdx.x * THREADS + threadIdx.x;
    if (e < E) perm[rowptr[tgt[e]] + ke[e]] = e;
}

// ---------------- per-node premix: G[n][o][16] = W_c^T f with norms folded ----------------
// layout per (n,o): [g0, g2, g1x,g1y,g1z, g3x,g3y,g3z, g4x,g4y,g4z, g5x,g5y,g5z, pad, pad]

__global__ __launch_bounds__(THREADS, 4) void k_premix(const float* __restrict__ node,
                                                       const float* __restrict__ W,
                                                       float* __restrict__ G, int N) {
    __shared__ float sW[384];
    for (int t = threadIdx.x; t < 384; t += THREADS) sW[t] = W[t];
    __syncthreads();

    int gid = blockIdx.x * THREADS + threadIdx.x;
    int n = gid >> 3;
    int o = gid & 7;
    if (n >= N) return;

    constexpr float IS3 = 0.57735026918962576f;
    constexpr float IS6 = 0.40824829046386302f;

    float f[32];
    {
        const float4* nr = (const float4*)(node + (size_t)n * 32);
        #pragma unroll
        for (int i = 0; i < 8; ++i) {
            float4 v = nr[i];
            f[4*i+0]=v.x; f[4*i+1]=v.y; f[4*i+2]=v.z; f[4*i+3]=v.w;
        }
    }

    float g0=0.f, g2=0.f;
    float g1x=0.f,g1y=0.f,g1z=0.f, g3x=0.f,g3y=0.f,g3z=0.f;
    float g4x=0.f,g4y=0.f,g4z=0.f, g5x=0.f,g5y=0.f,g5z=0.f;

    #pragma unroll
    for (int i = 0; i < 8; ++i) {
        const float f0 = f[i];
        const float x = f[8+3*i+0], y = f[8+3*i+1], z = f[8+3*i+2];
        const float w0 = sW[0*64 + i*8 + o];
        const float w1 = sW[1*64 + i*8 + o];
        const float w2 = sW[2*64 + i*8 + o];
        const float w3 = sW[3*64 + i*8 + o];
        const float w4 = sW[4*64 + i*8 + o];
        const float w5 = sW[5*64 + i*8 + o];
        g0 += w0*f0;  g2 += w2*f0;
        g1x += w1*x; g1y += w1*y; g1z += w1*z;
        g3x += w3*x; g3y += w3*y; g3z += w3*z;
        g4x += w4*x; g4y += w4*y; g4z += w4*z;
        g5x += w5*x; g5y += w5*y; g5z += w5*z;
    }

    float4* gr = (float4*)(G + ((size_t)n * 8 + o) * 16);
    gr[0] = make_float4(g0, g2*IS3, g1x*IS3, g1y*IS3);
    gr[1] = make_float4(g1z*IS3, g3x*IS3, g3y*IS3, g3z*IS3);
    gr[2] = make_float4(g4x*IS6, g4y*IS6, g4z*IS6, g5x);
    gr[3] = make_float4(g5y, g5z, 0.f, 0.f);
}

// ---------------- fused per-node aggregation (computes messages inline) ----------------

__global__ __launch_bounds__(THREADS, 4) void k_aggfused(
    const int*   __restrict__ eidx,      // src row of edge_index
    const float* __restrict__ sh0,
    const float* __restrict__ sh1,
    const float* __restrict__ sh2,
    const int*   __restrict__ rowptr,
    const int*   __restrict__ perm,
    const float* __restrict__ G,
    float*       __restrict__ out, int N)
{
    int gid = blockIdx.x * THREADS + threadIdx.x;
    int n = gid >> 3;
    int o = gid & 7;
    if (n >= N) return;

    constexpr float IS10 = 0.31622776601683794f;
    constexpr float IS30 = 0.18257418583505536f;

    const int jbeg = rowptr[n];
    const int jend = rowptr[n + 1];

    float acc_s = 0.f, ax = 0.f, ay = 0.f, az = 0.f;

    int j = jbeg;
    int ecur = 0, scur = 0;
    if (j < jend) { ecur = perm[j]; scur = eidx[ecur]; }

    while (j < jend) {
        // prefetch next edge's id/src to overlap the dependent chain
        int jn = j + 1;
        int enxt = 0, snxt = 0;
        if (jn < jend) { enxt = perm[jn]; snxt = eidx[enxt]; }

        const float s  = sh0[ecur];
        const float u0 = sh1[3*ecur+0], u1 = sh1[3*ecur+1], u2 = sh1[3*ecur+2];
        const float q0 = sh2[5*ecur+0], q1 = sh2[5*ecur+1], q2 = sh2[5*ecur+2],
                    q3 = sh2[5*ecur+3], q4 = sh2[5*ecur+4];

        const float4* gr = (const float4*)(G + ((size_t)scur * 8 + o) * 16);
        const float4 a = gr[0];
        const float4 b = gr[1];
        const float4 c = gr[2];
        const float4 d = gr[3];
        // a = [g0, g2', g1x', g1y'], b = [g1z', g3x', g3y', g3z']
        // c = [g4x', g4y', g4z', g5x], d = [g5y, g5z, -, -]

        const float Q00 = -q2*IS30 - q4*IS10;
        const float Q01 =  q1*IS10;
        const float Q02 =  q0*IS10;
        const float Q11 =  2.0f*q2*IS30;
        const float Q12 =  q3*IS10;
        const float Q22 = -q2*IS30 + q4*IS10;

        // l=0 output: s*g0 + u . g3'
        acc_s += s*a.x + u0*b.y + u1*b.z + u2*b.w;

        // l=1 output: s*g1' + g2'*u + u x g4' + Q . g5
        ax += s*a.z + a.y*u0 + (u1*c.z - u2*c.y) + (Q00*c.w + Q01*d.x + Q02*d.y);
        ay += s*a.w + a.y*u1 + (u2*c.x - u0*c.z) + (Q01*c.w + Q11*d.x + Q12*d.y);
        az += s*b.x + a.y*u2 + (u0*c.y - u1*c.x) + (Q02*c.w + Q12*d.x + Q22*d.y);

        j = jn; ecur = enxt; scur = snxt;
    }

    float* orow = out + (size_t)n * 32;
    orow[o] = acc_s;
    orow[8 + 3*o + 0] = ax;
    orow[8 + 3*o + 1] = ay;
    orow[8 + 3*o + 2] = az;
}

// ---------------- fallback: round-1 atomic kernel ----------------

__global__ __launch_bounds__(THREADS) void msg_kernel_atomic(
    const float* __restrict__ node,
    const int*   __restrict__ eidx,
    const float* __restrict__ sh0,
    const float* __restrict__ sh1,
    const float* __restrict__ sh2,
    const float* __restrict__ W,
    float*       __restrict__ out,
    int E)
{
    __shared__ float sW[384];
    for (int t = threadIdx.x; t < 384; t += THREADS) sW[t] = W[t];
    __syncthreads();

    int e = blockIdx.x * THREADS + threadIdx.x;
    if (e >= E) return;

    constexpr float IS3  = 0.57735026918962576f;
    constexpr float IS6  = 0.40824829046386302f;
    constexpr float IS10 = 0.31622776601683794f;
    constexpr float IS30 = 0.18257418583505536f;

    const int src = eidx[e];
    const int tgt = eidx[E + e];

    const float s  = sh0[e];
    const float u0 = sh1[3*e+0], u1 = sh1[3*e+1], u2 = sh1[3*e+2];
    const float q0 = sh2[5*e+0], q1 = sh2[5*e+1], q2 = sh2[5*e+2],
                q3 = sh2[5*e+3], q4 = sh2[5*e+4];

    const float Q00 = -q2*IS30 - q4*IS10;
    const float Q01 =  q1*IS10;
    const float Q02 =  q0*IS10;
    const float Q11 =  2.0f*q2*IS30;
    const float Q12 =  q3*IS10;
    const float Q22 = -q2*IS30 + q4*IS10;

    float f[32];
    {
        const float4* nr = (const float4*)(node + (size_t)src * 32);
        #pragma unroll
        for (int i = 0; i < 8; ++i) {
            float4 v = nr[i];
            f[4*i+0]=v.x; f[4*i+1]=v.y; f[4*i+2]=v.z; f[4*i+3]=v.w;
        }
    }

    float msg[32];
    #pragma unroll
    for (int j = 0; j < 32; ++j) msg[j] = 0.0f;

    const float s13 = s * IS3;

    #pragma unroll
    for (int i = 0; i < 8; ++i) {
        const float f0i = f[i];
        const float x = f[8+3*i+0], y = f[8+3*i+1], z = f[8+3*i+2];
        const float c0  = s * f0i;
        const float c3  = IS3 * (u0*x + u1*y + u2*z);
        const float p2  = IS3 * f0i;
        const float c1x = s13*x, c1y = s13*y, c1z = s13*z;
        const float c2x = p2*u0, c2y = p2*u1, c2z = p2*u2;
        const float c4x = IS6*(u1*z - u2*y);
        const float c4y = IS6*(u2*x - u0*z);
        const float c4z = IS6*(u0*y - u1*x);
        const float c5x = Q00*x + Q01*y + Q02*z;
        const float c5y = Q01*x + Q11*y + Q12*z;
        const float c5z = Q02*x + Q12*y + Q22*z;

        float wr[6][8];
        #pragma unroll
        for (int c = 0; c < 6; ++c) {
            float4 a = *(const float4*)&sW[c*64 + i*8 + 0];
            float4 b = *(const float4*)&sW[c*64 + i*8 + 4];
            wr[c][0]=a.x; wr[c][1]=a.y; wr[c][2]=a.z; wr[c][3]=a.w;
            wr[c][4]=b.x; wr[c][5]=b.y; wr[c][6]=b.z; wr[c][7]=b.w;
        }

        #pragma unroll
        for (int o = 0; o < 8; ++o) {
            msg[o] += wr[0][o]*c0 + wr[3][o]*c3;
            msg[8+3*o+0] += wr[1][o]*c1x + wr[2][o]*c2x + wr[4][o]*c4x + wr[5][o]*c5x;
            msg[8+3*o+1] += wr[1][o]*c1y + wr[2][o]*c2y + wr[4][o]*c4y + wr[5][o]*c5y;
            msg[8+3*o+2] += wr[1][o]*c1z + wr[2][o]*c2z + wr[4][o]*c4z + wr[5][o]*c5z;
        }
    }

    float* orow = out + (size_t)tgt * 32;
    #pragma unroll
    for (int j = 0; j < 32; ++j) unsafeAtomicAdd(orow + j, msg[j]);
}

// ---------------- host ----------------

extern "C" void kernel_launch(void* const* d_in, const int* in_sizes, int n_in,
                              void* d_out, int out_size, void* d_ws, size_t ws_size,
                              hipStream_t stream) {
    const float* node = (const float*)d_in[0];
    const int*   eidx = (const int*)d_in[1];
    const float* sh0  = (const float*)d_in[2];
    const float* sh1  = (const float*)d_in[3];
    const float* sh2  = (const float*)d_in[4];
    const float* W    = (const float*)d_in[5];
    float* out = (float*)d_out;

    const int E = in_sizes[2];          // sh0 has E elements
    const int N = in_sizes[0] / 32;     // node_irreps is [N, 32]
    const int NB = (N + 1023) / 1024;

    // ws layout (ints): rowptr[N+1] | cnt[N] | bsum[1024] | ke[E] | perm[E] | (align 128B) G[N*128] floats
    size_t int_words = (size_t)(N + 1) + N + 1024 + (size_t)E + (size_t)E;
    size_t g_off_w   = (int_words + 31) & ~(size_t)31;       // 128B-align G
    size_t need      = (g_off_w + (size_t)N * 128) * sizeof(float);

    if (ws_size >= need && NB <= 1024) {
        int* rowptr = (int*)d_ws;
        int* cnt    = rowptr + (N + 1);
        int* bsum   = cnt + N;
        int* ke     = bsum + 1024;
        int* perm   = ke + E;
        float* G    = (float*)d_ws + g_off_w;

        hipMemsetAsync(cnt, 0, (size_t)N * sizeof(int), stream);

        k_hist2<<<(E + THREADS - 1) / THREADS, THREADS, 0, stream>>>(eidx + E, cnt, ke, E);
        k_scan_partial<<<NB, THREADS, 0, stream>>>(cnt, bsum, N);
        k_scan_bsum<<<1, 1024, 0, stream>>>(bsum, NB);
        k_scan_final<<<NB, THREADS, 0, stream>>>(cnt, bsum, rowptr, N, E);
        k_perm<<<(E + THREADS - 1) / THREADS, THREADS, 0, stream>>>(eidx + E, ke, rowptr, perm, E);

        k_premix<<<((N * 8) + THREADS - 1) / THREADS, THREADS, 0, stream>>>(node, W, G, N);

        k_aggfused<<<((N * 8) + THREADS - 1) / THREADS, THREADS, 0, stream>>>(
            eidx, sh0, sh1, sh2, rowptr, perm, G, out, N);
    } else {
        hipMemsetAsync(d_out, 0, (size_t)out_size * sizeof(float), stream);
        msg_kernel_atomic<<<(E + THREADS - 1) / THREADS, THREADS, 0, stream>>>(
            node, eidx, sh0, sh1, sh2, W, out, E);
    }
}

// Round 4
// 355.219 us; speedup vs baseline: 1.3597x; 1.3597x over previous
//
#include <hip/hip_runtime.h>

#define THREADS 256

// ---------------- CSR build ----------------

// counts + per-target rank (atomic return value)
__global__ __launch_bounds__(THREADS) void k_hist2(const int* __restrict__ tgt,
                                                   int* __restrict__ cnt,
                                                   int* __restrict__ ke, int E) {
    int e = blockIdx.x * THREADS + threadIdx.x;
    if (e < E) ke[e] = atomicAdd(&cnt[tgt[e]], 1);
}

// per-1024-chunk totals
__global__ __launch_bounds__(THREADS) void k_scan_partial(const int* __restrict__ cnt,
                                                          int* __restrict__ bsum, int N) {
    __shared__ int lds[THREADS];
    int base = blockIdx.x * 1024 + threadIdx.x * 4;
    int s = 0;
    #pragma unroll
    for (int k = 0; k < 4; ++k) { int i = base + k; if (i < N) s += cnt[i]; }
    lds[threadIdx.x] = s; __syncthreads();
    for (int off = THREADS / 2; off > 0; off >>= 1) {
        if (threadIdx.x < off) lds[threadIdx.x] += lds[threadIdx.x + off];
        __syncthreads();
    }
    if (threadIdx.x == 0) bsum[blockIdx.x] = lds[0];
}

// single-block exclusive scan of block sums (NB <= 1024)
__global__ __launch_bounds__(1024) void k_scan_bsum(int* __restrict__ bsum, int NB) {
    __shared__ int lds[1024];
    int t = threadIdx.x;
    int v = (t < NB) ? bsum[t] : 0;
    lds[t] = v; __syncthreads();
    for (int off = 1; off < 1024; off <<= 1) {
        int x = (t >= off) ? lds[t - off] : 0;
        __syncthreads();
        lds[t] += x;
        __syncthreads();
    }
    if (t < NB) bsum[t] = lds[t] - v;   // exclusive
}

__global__ __launch_bounds__(THREADS) void k_scan_final(int* __restrict__ cnt,
                                                        const int* __restrict__ bsum,
                                                        int* __restrict__ rowptr,
                                                        int N, int E) {
    __shared__ int lds[THREADS];
    int base = blockIdx.x * 1024 + threadIdx.x * 4;
    int v[4]; int local = 0;
    #pragma unroll
    for (int k = 0; k < 4; ++k) {
        int i = base + k;
        v[k] = (i < N) ? cnt[i] : 0;
        local += v[k];
    }
    lds[threadIdx.x] = local; __syncthreads();
    for (int off = 1; off < THREADS; off <<= 1) {
        int x = (threadIdx.x >= off) ? lds[threadIdx.x - off] : 0;
        __syncthreads();
        lds[threadIdx.x] += x;
        __syncthreads();
    }
    int p = lds[threadIdx.x] - local + bsum[blockIdx.x];
    #pragma unroll
    for (int k = 0; k < 4; ++k) {
        int i = base + k;
        if (i < N) { rowptr[i] = p; p += v[k]; }
    }
    if (blockIdx.x == 0 && threadIdx.x == 0) rowptr[N] = E;
}

// ---------------- scatter edge payloads into CSR order ----------------
// payload row (16 floats, 64B): [s, u0,u1,u2, q0,q1,q2,q3, q4, src(bits), 0,0, 0,0,0,0]

__global__ __launch_bounds__(THREADS) void k_scatter(const int* __restrict__ eidx,
                                                     const int* __restrict__ ke,
                                                     const int* __restrict__ rowptr,
                                                     const float* __restrict__ sh0,
                                                     const float* __restrict__ sh1,
                                                     const float* __restrict__ sh2,
                                                     float* __restrict__ payload,
                                                     int E) {
    int e = blockIdx.x * THREADS + threadIdx.x;
    if (e >= E) return;
    int src = eidx[e];
    int tgt = eidx[E + e];
    int pos = rowptr[tgt] + ke[e];

    float4 p0 = make_float4(sh0[e], sh1[3*e+0], sh1[3*e+1], sh1[3*e+2]);
    float4 p1 = make_float4(sh2[5*e+0], sh2[5*e+1], sh2[5*e+2], sh2[5*e+3]);
    float4 p2 = make_float4(sh2[5*e+4], __int_as_float(src), 0.f, 0.f);
    float4 p3 = make_float4(0.f, 0.f, 0.f, 0.f);

    float4* pr = (float4*)(payload + (size_t)pos * 16);
    pr[0] = p0; pr[1] = p1; pr[2] = p2; pr[3] = p3;   // full 64B line
}

// ---------------- fused aggregation in pre-W space + per-node postmix ----------------
// 8 threads per node; thread i = input channel i. 32 nodes per block.

__global__ __launch_bounds__(THREADS) void k_agg2(const float* __restrict__ node,
                                                  const int*   __restrict__ rowptr,
                                                  const float* __restrict__ payload,
                                                  const float* __restrict__ W,
                                                  float*       __restrict__ out, int N) {
    __shared__ float sW[384];
    __shared__ float sAcc[32 * 8 * 14];    // [nodeSlot][i][14]
    for (int t = threadIdx.x; t < 384; t += THREADS) sW[t] = W[t];
    __syncthreads();

    constexpr float IS3  = 0.57735026918962576f;
    constexpr float IS6  = 0.40824829046386302f;
    constexpr float IS10 = 0.31622776601683794f;
    constexpr float IS30 = 0.18257418583505536f;

    const int nodeSlot = threadIdx.x >> 3;
    const int i        = threadIdx.x & 7;
    const int n        = blockIdx.x * 32 + nodeSlot;

    float a[14];
    #pragma unroll
    for (int k = 0; k < 14; ++k) a[k] = 0.f;

    if (n < N) {
        const int jbeg = rowptr[n];
        const int jend = rowptr[n + 1];
        for (int j = jbeg; j < jend; ++j) {
            const float4* pr = (const float4*)(payload + (size_t)j * 16);
            const float4 p0 = pr[0];
            const float4 p1 = pr[1];
            const float4 p2 = pr[2];
            const int src = __float_as_int(p2.y);

            const float* nr = node + (size_t)src * 32;
            const float f0 = nr[i];
            const float x  = nr[8 + 3*i + 0];
            const float y  = nr[8 + 3*i + 1];
            const float z  = nr[8 + 3*i + 2];

            const float s  = p0.x, u0 = p0.y, u1 = p0.z, u2 = p0.w;
            const float q0 = p1.x, q1 = p1.y, q2 = p1.z, q3 = p1.w, q4 = p2.x;

            const float Q00 = -q2*IS30 - q4*IS10;
            const float Q01 =  q1*IS10;
            const float Q02 =  q0*IS10;
            const float Q11 =  2.0f*q2*IS30;
            const float Q12 =  q3*IS10;
            const float Q22 = -q2*IS30 + q4*IS10;

            a[0]  += s * f0;                       // c0
            a[1]  += u0*x + u1*y + u2*z;           // c3 (pre IS3)
            a[2]  += s * x;                        // c1 (pre IS3)
            a[3]  += s * y;
            a[4]  += s * z;
            a[5]  += f0 * u0;                      // c2 (pre IS3)
            a[6]  += f0 * u1;
            a[7]  += f0 * u2;
            a[8]  += u1*z - u2*y;                  // c4 (pre IS6)
            a[9]  += u2*x - u0*z;
            a[10] += u0*y - u1*x;
            a[11] += Q00*x + Q01*y + Q02*z;        // c5
            a[12] += Q01*x + Q11*y + Q12*z;
            a[13] += Q02*x + Q12*y + Q22*z;
        }
    }

    // fold norms (linear, once per node)
    #pragma unroll
    for (int k = 1; k < 8; ++k) a[k] *= IS3;
    #pragma unroll
    for (int k = 8; k < 11; ++k) a[k] *= IS6;

    float* myAcc = &sAcc[(nodeSlot * 8 + i) * 14];
    #pragma unroll
    for (int k = 0; k < 14; ++k) myAcc[k] = a[k];
    __syncthreads();

    if (n < N) {
        const int o = i;
        float o0 = 0.f, ox = 0.f, oy = 0.f, oz = 0.f;
        #pragma unroll
        for (int ii = 0; ii < 8; ++ii) {
            const float* A = &sAcc[(nodeSlot * 8 + ii) * 14];
            const float w0 = sW[  0 + ii*8 + o];
            const float w1 = sW[ 64 + ii*8 + o];
            const float w2 = sW[128 + ii*8 + o];
            const float w3 = sW[192 + ii*8 + o];
            const float w4 = sW[256 + ii*8 + o];
            const float w5 = sW[320 + ii*8 + o];
            o0 += w0*A[0]  + w3*A[1];
            ox += w1*A[2]  + w2*A[5] + w4*A[8]  + w5*A[11];
            oy += w1*A[3]  + w2*A[6] + w4*A[9]  + w5*A[12];
            oz += w1*A[4]  + w2*A[7] + w4*A[10] + w5*A[13];
        }
        float* orow = out + (size_t)n * 32;
        orow[o]         = o0;
        orow[8 + 3*o+0] = ox;
        orow[8 + 3*o+1] = oy;
        orow[8 + 3*o+2] = oz;
    }
}

// ---------------- fallback: round-1 atomic kernel ----------------

__global__ __launch_bounds__(THREADS) void msg_kernel_atomic(
    const float* __restrict__ node,
    const int*   __restrict__ eidx,
    const float* __restrict__ sh0,
    const float* __restrict__ sh1,
    const float* __restrict__ sh2,
    const float* __restrict__ W,
    float*       __restrict__ out,
    int E)
{
    __shared__ float sW[384];
    for (int t = threadIdx.x; t < 384; t += THREADS) sW[t] = W[t];
    __syncthreads();

    int e = blockIdx.x * THREADS + threadIdx.x;
    if (e >= E) return;

    constexpr float IS3  = 0.57735026918962576f;
    constexpr float IS6  = 0.40824829046386302f;
    constexpr float IS10 = 0.31622776601683794f;
    constexpr float IS30 = 0.18257418583505536f;

    const int src = eidx[e];
    const int tgt = eidx[E + e];

    const float s  = sh0[e];
    const float u0 = sh1[3*e+0], u1 = sh1[3*e+1], u2 = sh1[3*e+2];
    const float q0 = sh2[5*e+0], q1 = sh2[5*e+1], q2 = sh2[5*e+2],
                q3 = sh2[5*e+3], q4 = sh2[5*e+4];

    const float Q00 = -q2*IS30 - q4*IS10;
    const float Q01 =  q1*IS10;
    const float Q02 =  q0*IS10;
    const float Q11 =  2.0f*q2*IS30;
    const float Q12 =  q3*IS10;
    const float Q22 = -q2*IS30 + q4*IS10;

    float f[32];
    {
        const float4* nr = (const float4*)(node + (size_t)src * 32);
        #pragma unroll
        for (int i = 0; i < 8; ++i) {
            float4 v = nr[i];
            f[4*i+0]=v.x; f[4*i+1]=v.y; f[4*i+2]=v.z; f[4*i+3]=v.w;
        }
    }

    float msg[32];
    #pragma unroll
    for (int j = 0; j < 32; ++j) msg[j] = 0.0f;

    const float s13 = s * IS3;

    #pragma unroll
    for (int i = 0; i < 8; ++i) {
        const float f0i = f[i];
        const float x = f[8+3*i+0], y = f[8+3*i+1], z = f[8+3*i+2];
        const float c0  = s * f0i;
        const float c3  = IS3 * (u0*x + u1*y + u2*z);
        const float p2  = IS3 * f0i;
        const float c1x = s13*x, c1y = s13*y, c1z = s13*z;
        const float c2x = p2*u0, c2y = p2*u1, c2z = p2*u2;
        const float c4x = IS6*(u1*z - u2*y);
        const float c4y = IS6*(u2*x - u0*z);
        const float c4z = IS6*(u0*y - u1*x);
        const float c5x = Q00*x + Q01*y + Q02*z;
        const float c5y = Q01*x + Q11*y + Q12*z;
        const float c5z = Q02*x + Q12*y + Q22*z;

        float wr[6][8];
        #pragma unroll
        for (int c = 0; c < 6; ++c) {
            float4 aa = *(const float4*)&sW[c*64 + i*8 + 0];
            float4 bb = *(const float4*)&sW[c*64 + i*8 + 4];
            wr[c][0]=aa.x; wr[c][1]=aa.y; wr[c][2]=aa.z; wr[c][3]=aa.w;
            wr[c][4]=bb.x; wr[c][5]=bb.y; wr[c][6]=bb.z; wr[c][7]=bb.w;
        }

        #pragma unroll
        for (int o = 0; o < 8; ++o) {
            msg[o] += wr[0][o]*c0 + wr[3][o]*c3;
            msg[8+3*o+0] += wr[1][o]*c1x + wr[2][o]*c2x + wr[4][o]*c4x + wr[5][o]*c5x;
            msg[8+3*o+1] += wr[1][o]*c1y + wr[2][o]*c2y + wr[4][o]*c4y + wr[5][o]*c5y;
            msg[8+3*o+2] += wr[1][o]*c1z + wr[2][o]*c2z + wr[4][o]*c4z + wr[5][o]*c5z;
        }
    }

    float* orow = out + (size_t)tgt * 32;
    #pragma unroll
    for (int j = 0; j < 32; ++j) unsafeAtomicAdd(orow + j, msg[j]);
}

// ---------------- host ----------------

extern "C" void kernel_launch(void* const* d_in, const int* in_sizes, int n_in,
                              void* d_out, int out_size, void* d_ws, size_t ws_size,
                              hipStream_t stream) {
    const float* node = (const float*)d_in[0];
    const int*   eidx = (const int*)d_in[1];
    const float* sh0  = (const float*)d_in[2];
    const float* sh1  = (const float*)d_in[3];
    const float* sh2  = (const float*)d_in[4];
    const float* W    = (const float*)d_in[5];
    float* out = (float*)d_out;

    const int E = in_sizes[2];          // sh0 has E elements
    const int N = in_sizes[0] / 32;     // node_irreps is [N, 32]
    const int NB = (N + 1023) / 1024;

    // ws layout (words): rowptr[N+1] | cnt[N] | bsum[1024] | ke[E] | (align 64B) payload[E*16]
    size_t int_words = (size_t)(N + 1) + N + 1024 + (size_t)E;
    size_t pay_off_w = (int_words + 15) & ~(size_t)15;       // 64B-align payload
    size_t need      = (pay_off_w + (size_t)E * 16) * sizeof(float);

    if (ws_size >= need && NB <= 1024) {
        int* rowptr = (int*)d_ws;
        int* cnt    = rowptr + (N + 1);
        int* bsum   = cnt + N;
        int* ke     = bsum + 1024;
        float* payload = (float*)d_ws + pay_off_w;

        hipMemsetAsync(cnt, 0, (size_t)N * sizeof(int), stream);

        k_hist2<<<(E + THREADS - 1) / THREADS, THREADS, 0, stream>>>(eidx + E, cnt, ke, E);
        k_scan_partial<<<NB, THREADS, 0, stream>>>(cnt, bsum, N);
        k_scan_bsum<<<1, 1024, 0, stream>>>(bsum, NB);
        k_scan_final<<<NB, THREADS, 0, stream>>>(cnt, bsum, rowptr, N, E);
        k_scatter<<<(E + THREADS - 1) / THREADS, THREADS, 0, stream>>>(
            eidx, ke, rowptr, sh0, sh1, sh2, payload, E);

        k_agg2<<<(N + 31) / 32, THREADS, 0, stream>>>(node, rowptr, payload, W, out, N);
    } else {
        hipMemsetAsync(d_out, 0, (size_t)out_size * sizeof(float), stream);
        msg_kernel_atomic<<<(E + THREADS - 1) / THREADS, THREADS, 0, stream>>>(
            node, eidx, sh0, sh1, sh2, W, out, E);
    }
}

// Round 5
// 350.952 us; speedup vs baseline: 1.3763x; 1.0122x over previous
//
#include <hip/hip_runtime.h>

#define THREADS 256

// ---------------- CSR build ----------------

// counts only
__global__ __launch_bounds__(THREADS) void k_hist(const int* __restrict__ tgt,
                                                  int* __restrict__ cnt, int E) {
    int e = blockIdx.x * THREADS + threadIdx.x;
    if (e < E) atomicAdd(&cnt[tgt[e]], 1);
}

// per-1024-chunk totals
__global__ __launch_bounds__(THREADS) void k_scan_partial(const int* __restrict__ cnt,
                                                          int* __restrict__ bsum, int N) {
    __shared__ int lds[THREADS];
    int base = blockIdx.x * 1024 + threadIdx.x * 4;
    int s = 0;
    #pragma unroll
    for (int k = 0; k < 4; ++k) { int i = base + k; if (i < N) s += cnt[i]; }
    lds[threadIdx.x] = s; __syncthreads();
    for (int off = THREADS / 2; off > 0; off >>= 1) {
        if (threadIdx.x < off) lds[threadIdx.x] += lds[threadIdx.x + off];
        __syncthreads();
    }
    if (threadIdx.x == 0) bsum[blockIdx.x] = lds[0];
}

// single-block exclusive scan of block sums (NB <= 1024)
__global__ __launch_bounds__(1024) void k_scan_bsum(int* __restrict__ bsum, int NB) {
    __shared__ int lds[1024];
    int t = threadIdx.x;
    int v = (t < NB) ? bsum[t] : 0;
    lds[t] = v; __syncthreads();
    for (int off = 1; off < 1024; off <<= 1) {
        int x = (t >= off) ? lds[t - off] : 0;
        __syncthreads();
        lds[t] += x;
        __syncthreads();
    }
    if (t < NB) bsum[t] = lds[t] - v;   // exclusive
}

// writes rowptr AND a working cursor copy
__global__ __launch_bounds__(THREADS) void k_scan_final(const int* __restrict__ cnt,
                                                        const int* __restrict__ bsum,
                                                        int* __restrict__ rowptr,
                                                        int* __restrict__ cursor,
                                                        int N, int E) {
    __shared__ int lds[THREADS];
    int base = blockIdx.x * 1024 + threadIdx.x * 4;
    int v[4]; int local = 0;
    #pragma unroll
    for (int k = 0; k < 4; ++k) {
        int i = base + k;
        v[k] = (i < N) ? cnt[i] : 0;
        local += v[k];
    }
    lds[threadIdx.x] = local; __syncthreads();
    for (int off = 1; off < THREADS; off <<= 1) {
        int x = (threadIdx.x >= off) ? lds[threadIdx.x - off] : 0;
        __syncthreads();
        lds[threadIdx.x] += x;
        __syncthreads();
    }
    int p = lds[threadIdx.x] - local + bsum[blockIdx.x];
    #pragma unroll
    for (int k = 0; k < 4; ++k) {
        int i = base + k;
        if (i < N) { rowptr[i] = p; cursor[i] = p; p += v[k]; }
    }
    if (blockIdx.x == 0 && threadIdx.x == 0) rowptr[N] = E;
}

// ---------------- scatter edge payloads into CSR order ----------------
// payload row (stride 16 floats = 64B, 40B used):
//   [s, u0,u1,u2 | q0,q1,q2,q3 | q4, src(bits)]

__global__ __launch_bounds__(THREADS) void k_scatter(const int* __restrict__ eidx,
                                                     int* __restrict__ cursor,
                                                     const float* __restrict__ sh0,
                                                     const float* __restrict__ sh1,
                                                     const float* __restrict__ sh2,
                                                     float* __restrict__ payload,
                                                     int E) {
    int e = blockIdx.x * THREADS + threadIdx.x;
    if (e >= E) return;
    int src = eidx[e];
    int tgt = eidx[E + e];

    float4 p0 = make_float4(sh0[e], sh1[3*e+0], sh1[3*e+1], sh1[3*e+2]);
    float4 p1 = make_float4(sh2[5*e+0], sh2[5*e+1], sh2[5*e+2], sh2[5*e+3]);
    float2 p2 = make_float2(sh2[5*e+4], __int_as_float(src));

    int pos = atomicAdd(&cursor[tgt], 1);

    float* pr = payload + (size_t)pos * 16;
    *(float4*)(pr + 0) = p0;
    *(float4*)(pr + 4) = p1;
    *(float2*)(pr + 8) = p2;
}

// ---------------- fused aggregation in pre-W space + per-node postmix ----------------
// 8 threads per node; thread i = input channel i. 32 nodes per block.

#define ACC_STRIDE 15   // 14 used +1 pad to break LDS bank conflicts

__global__ __launch_bounds__(THREADS) void k_agg2(const float* __restrict__ node,
                                                  const int*   __restrict__ rowptr,
                                                  const float* __restrict__ payload,
                                                  const float* __restrict__ W,
                                                  float*       __restrict__ out, int N) {
    __shared__ float sW[384];
    __shared__ float sAcc[32 * 8 * ACC_STRIDE];
    for (int t = threadIdx.x; t < 384; t += THREADS) sW[t] = W[t];
    __syncthreads();

    constexpr float IS3  = 0.57735026918962576f;
    constexpr float IS6  = 0.40824829046386302f;
    constexpr float IS10 = 0.31622776601683794f;
    constexpr float IS30 = 0.18257418583505536f;

    const int nodeSlot = threadIdx.x >> 3;
    const int i        = threadIdx.x & 7;
    const int n        = blockIdx.x * 32 + nodeSlot;

    float a[14];
    #pragma unroll
    for (int k = 0; k < 14; ++k) a[k] = 0.f;

    if (n < N) {
        const int jbeg = rowptr[n];
        const int jend = rowptr[n + 1];

        if (jbeg < jend) {
            // software pipeline: payload[j+1] loads while node-row[j] is in flight
            const float* pr = payload + (size_t)jbeg * 16;
            float4 c0 = *(const float4*)(pr + 0);
            float4 c1 = *(const float4*)(pr + 4);
            float2 c2 = *(const float2*)(pr + 8);

            for (int j = jbeg; j < jend; ++j) {
                float4 n0, n1; float2 n2;
                if (j + 1 < jend) {
                    const float* prn = payload + (size_t)(j + 1) * 16;
                    n0 = *(const float4*)(prn + 0);
                    n1 = *(const float4*)(prn + 4);
                    n2 = *(const float2*)(prn + 8);
                }

                const int src = __float_as_int(c2.y);
                const float* nr = node + (size_t)src * 32;
                const float f0 = nr[i];
                const float x  = nr[8 + 3*i + 0];
                const float y  = nr[8 + 3*i + 1];
                const float z  = nr[8 + 3*i + 2];

                const float s  = c0.x, u0 = c0.y, u1 = c0.z, u2 = c0.w;
                const float q0 = c1.x, q1 = c1.y, q2 = c1.z, q3 = c1.w, q4 = c2.x;

                const float Q00 = -q2*IS30 - q4*IS10;
                const float Q01 =  q1*IS10;
                const float Q02 =  q0*IS10;
                const float Q11 =  2.0f*q2*IS30;
                const float Q12 =  q3*IS10;
                const float Q22 = -q2*IS30 + q4*IS10;

                a[0]  += s * f0;                       // c0
                a[1]  += u0*x + u1*y + u2*z;           // c3 (pre IS3)
                a[2]  += s * x;                        // c1 (pre IS3)
                a[3]  += s * y;
                a[4]  += s * z;
                a[5]  += f0 * u0;                      // c2 (pre IS3)
                a[6]  += f0 * u1;
                a[7]  += f0 * u2;
                a[8]  += u1*z - u2*y;                  // c4 (pre IS6)
                a[9]  += u2*x - u0*z;
                a[10] += u0*y - u1*x;
                a[11] += Q00*x + Q01*y + Q02*z;        // c5
                a[12] += Q01*x + Q11*y + Q12*z;
                a[13] += Q02*x + Q12*y + Q22*z;

                c0 = n0; c1 = n1; c2 = n2;
            }
        }
    }

    // fold norms (linear, once per node)
    #pragma unroll
    for (int k = 1; k < 8; ++k) a[k] *= IS3;
    #pragma unroll
    for (int k = 8; k < 11; ++k) a[k] *= IS6;

    float* myAcc = &sAcc[(nodeSlot * 8 + i) * ACC_STRIDE];
    #pragma unroll
    for (int k = 0; k < 14; ++k) myAcc[k] = a[k];
    __syncthreads();

    if (n < N) {
        const int o = i;
        float o0 = 0.f, ox = 0.f, oy = 0.f, oz = 0.f;
        #pragma unroll
        for (int ii = 0; ii < 8; ++ii) {
            const float* A = &sAcc[(nodeSlot * 8 + ii) * ACC_STRIDE];
            const float w0 = sW[  0 + ii*8 + o];
            const float w1 = sW[ 64 + ii*8 + o];
            const float w2 = sW[128 + ii*8 + o];
            const float w3 = sW[192 + ii*8 + o];
            const float w4 = sW[256 + ii*8 + o];
            const float w5 = sW[320 + ii*8 + o];
            o0 += w0*A[0]  + w3*A[1];
            ox += w1*A[2]  + w2*A[5] + w4*A[8]  + w5*A[11];
            oy += w1*A[3]  + w2*A[6] + w4*A[9]  + w5*A[12];
            oz += w1*A[4]  + w2*A[7] + w4*A[10] + w5*A[13];
        }
        float* orow = out + (size_t)n * 32;
        orow[o]         = o0;
        orow[8 + 3*o+0] = ox;
        orow[8 + 3*o+1] = oy;
        orow[8 + 3*o+2] = oz;
    }
}

// ---------------- fallback: round-1 atomic kernel ----------------

__global__ __launch_bounds__(THREADS) void msg_kernel_atomic(
    const float* __restrict__ node,
    const int*   __restrict__ eidx,
    const float* __restrict__ sh0,
    const float* __restrict__ sh1,
    const float* __restrict__ sh2,
    const float* __restrict__ W,
    float*       __restrict__ out,
    int E)
{
    __shared__ float sW[384];
    for (int t = threadIdx.x; t < 384; t += THREADS) sW[t] = W[t];
    __syncthreads();

    int e = blockIdx.x * THREADS + threadIdx.x;
    if (e >= E) return;

    constexpr float IS3  = 0.57735026918962576f;
    constexpr float IS6  = 0.40824829046386302f;
    constexpr float IS10 = 0.31622776601683794f;
    constexpr float IS30 = 0.18257418583505536f;

    const int src = eidx[e];
    const int tgt = eidx[E + e];

    const float s  = sh0[e];
    const float u0 = sh1[3*e+0], u1 = sh1[3*e+1], u2 = sh1[3*e+2];
    const float q0 = sh2[5*e+0], q1 = sh2[5*e+1], q2 = sh2[5*e+2],
                q3 = sh2[5*e+3], q4 = sh2[5*e+4];

    const float Q00 = -q2*IS30 - q4*IS10;
    const float Q01 =  q1*IS10;
    const float Q02 =  q0*IS10;
    const float Q11 =  2.0f*q2*IS30;
    const float Q12 =  q3*IS10;
    const float Q22 = -q2*IS30 + q4*IS10;

    float f[32];
    {
        const float4* nr = (const float4*)(node + (size_t)src * 32);
        #pragma unroll
        for (int i = 0; i < 8; ++i) {
            float4 v = nr[i];
            f[4*i+0]=v.x; f[4*i+1]=v.y; f[4*i+2]=v.z; f[4*i+3]=v.w;
        }
    }

    float msg[32];
    #pragma unroll
    for (int j = 0; j < 32; ++j) msg[j] = 0.0f;

    const float s13 = s * IS3;

    #pragma unroll
    for (int i = 0; i < 8; ++i) {
        const float f0i = f[i];
        const float x = f[8+3*i+0], y = f[8+3*i+1], z = f[8+3*i+2];
        const float c0  = s * f0i;
        const float c3  = IS3 * (u0*x + u1*y + u2*z);
        const float p2  = IS3 * f0i;
        const float c1x = s13*x, c1y = s13*y, c1z = s13*z;
        const float c2x = p2*u0, c2y = p2*u1, c2z = p2*u2;
        const float c4x = IS6*(u1*z - u2*y);
        const float c4y = IS6*(u2*x - u0*z);
        const float c4z = IS6*(u0*y - u1*x);
        const float c5x = Q00*x + Q01*y + Q02*z;
        const float c5y = Q01*x + Q11*y + Q12*z;
        const float c5z = Q02*x + Q12*y + Q22*z;

        float wr[6][8];
        #pragma unroll
        for (int c = 0; c < 6; ++c) {
            float4 aa = *(const float4*)&sW[c*64 + i*8 + 0];
            float4 bb = *(const float4*)&sW[c*64 + i*8 + 4];
            wr[c][0]=aa.x; wr[c][1]=aa.y; wr[c][2]=aa.z; wr[c][3]=aa.w;
            wr[c][4]=bb.x; wr[c][5]=bb.y; wr[c][6]=bb.z; wr[c][7]=bb.w;
        }

        #pragma unroll
        for (int o = 0; o < 8; ++o) {
            msg[o] += wr[0][o]*c0 + wr[3][o]*c3;
            msg[8+3*o+0] += wr[1][o]*c1x + wr[2][o]*c2x + wr[4][o]*c4x + wr[5][o]*c5x;
            msg[8+3*o+1] += wr[1][o]*c1y + wr[2][o]*c2y + wr[4][o]*c4y + wr[5][o]*c5y;
            msg[8+3*o+2] += wr[1][o]*c1z + wr[2][o]*c2z + wr[4][o]*c4z + wr[5][o]*c5z;
        }
    }

    float* orow = out + (size_t)tgt * 32;
    #pragma unroll
    for (int j = 0; j < 32; ++j) unsafeAtomicAdd(orow + j, msg[j]);
}

// ---------------- host ----------------

extern "C" void kernel_launch(void* const* d_in, const int* in_sizes, int n_in,
                              void* d_out, int out_size, void* d_ws, size_t ws_size,
                              hipStream_t stream) {
    const float* node = (const float*)d_in[0];
    const int*   eidx = (const int*)d_in[1];
    const float* sh0  = (const float*)d_in[2];
    const float* sh1  = (const float*)d_in[3];
    const float* sh2  = (const float*)d_in[4];
    const float* W    = (const float*)d_in[5];
    float* out = (float*)d_out;

    const int E = in_sizes[2];          // sh0 has E elements
    const int N = in_sizes[0] / 32;     // node_irreps is [N, 32]
    const int NB = (N + 1023) / 1024;

    // ws layout (words): rowptr[N+1] | cursor[N] | cnt[N] | bsum[1024] | (align 64B) payload[E*16]
    size_t int_words = (size_t)(N + 1) + N + N + 1024;
    size_t pay_off_w = (int_words + 15) & ~(size_t)15;       // 64B-align payload
    size_t need      = (pay_off_w + (size_t)E * 16) * sizeof(float);

    if (ws_size >= need && NB <= 1024) {
        int* rowptr = (int*)d_ws;
        int* cursor = rowptr + (N + 1);
        int* cnt    = cursor + N;
        int* bsum   = cnt + N;
        float* payload = (float*)d_ws + pay_off_w;

        hipMemsetAsync(cnt, 0, (size_t)N * sizeof(int), stream);

        k_hist<<<(E + THREADS - 1) / THREADS, THREADS, 0, stream>>>(eidx + E, cnt, E);
        k_scan_partial<<<NB, THREADS, 0, stream>>>(cnt, bsum, N);
        k_scan_bsum<<<1, 1024, 0, stream>>>(bsum, NB);
        k_scan_final<<<NB, THREADS, 0, stream>>>(cnt, bsum, rowptr, cursor, N, E);
        k_scatter<<<(E + THREADS - 1) / THREADS, THREADS, 0, stream>>>(
            eidx, cursor, sh0, sh1, sh2, payload, E);

        k_agg2<<<(N + 31) / 32, THREADS, 0, stream>>>(node, rowptr, payload, W, out, N);
    } else {
        hipMemsetAsync(d_out, 0, (size_t)out_size * sizeof(float), stream);
        msg_kernel_atomic<<<(E + THREADS - 1) / THREADS, THREADS, 0, stream>>>(
            node, eidx, sh0, sh1, sh2, W, out, E);
    }
}